// Round 2
// baseline (615.848 us; speedup 1.0000x reference)
//
#include <hip/hip_runtime.h>
#include <hip/hip_bf16.h>
#include <math.h>

// ---------------------------------------------------------------------------
// 2-layer GCN on MI355X.
// Pipeline: build CSR (hist -> wave-scan offsets -> scatter)
//           xw1 = x @ W1            (fp32 tiled GEMM, 64x64)
//           h1  = relu(D^-1/2 A D^-1/2 xw1 + b1)   (CSR aggregation, 256 thr/node)
//           hw2 = h1 @ W2           (fp32 tiled GEMM)
//           out = softmax(D^-1/2 A D^-1/2 hw2 + b2) (CSR agg + wave softmax)
// ---------------------------------------------------------------------------

#define N_NODES 50000
#define N_EDGES 800000
#define D_IN    512
#define D_HID   256
#define D_OUT   64

// ---------------- workspace layout (bytes) ----------------
#define OFF_COUNTER 0
#define OFF_DEG     256
#define OFF_DINV    (OFF_DEG + 200704)
#define OFF_OFFS    (OFF_DINV + 200704)
#define OFF_CURSOR  (OFF_OFFS + 200704)
#define OFF_CSR     (OFF_CURSOR + 200704)
#define OFF_XW1     (OFF_CSR + 3200000)
#define OFF_H1      (OFF_XW1 + 51200000)
// total ~106.4 MB

// ---------------- CSR build ----------------

__global__ void k_hist(const int* __restrict__ dst, int* __restrict__ deg) {
    int e = blockIdx.x * 256 + threadIdx.x;
    if (e < N_EDGES) atomicAdd(&deg[dst[e]], 1);
}

// one wave per 64 nodes: computes dinv, and exclusive offsets via wave scan +
// one atomic per wave (offset blocks are non-monotonic across waves but form a
// valid disjoint partition of [0, N_EDGES) -- CSR order is irrelevant).
__global__ void k_scan(const int* __restrict__ deg, float* __restrict__ dinv,
                       int* __restrict__ offs, int* __restrict__ cursor,
                       int* __restrict__ counter) {
    int lane = threadIdx.x;           // block = 64
    int i = blockIdx.x * 64 + lane;
    int v = (i < N_NODES) ? deg[i] : 0;
    if (i < N_NODES) dinv[i] = rsqrtf((float)(v + 1));   // +1 self loop
    int incl = v;
    #pragma unroll
    for (int d = 1; d < 64; d <<= 1) {
        int t = __shfl_up(incl, d);
        if (lane >= d) incl += t;
    }
    int total = __shfl(incl, 63);
    int base = 0;
    if (lane == 63) base = atomicAdd(counter, total);
    base = __shfl(base, 63);
    int off = base + incl - v;        // exclusive within wave + wave base
    if (i < N_NODES) { offs[i] = off; cursor[i] = off; }
}

__global__ void k_scatter(const int* __restrict__ src, const int* __restrict__ dst,
                          int* __restrict__ cursor, int* __restrict__ csr) {
    int e = blockIdx.x * 256 + threadIdx.x;
    if (e < N_EDGES) {
        int d = dst[e];
        int slot = atomicAdd(&cursor[d], 1);
        csr[slot] = src[e];
    }
}

// ---------------- fp32 tiled GEMM: C[M][NF] = A[M][K] @ B[K][NF] ----------------
// 64x64 tile / block of 256 threads (16x16), 4x4 microtile, BK=16.
template<int K, int NF>
__global__ __launch_bounds__(256) void k_gemm(const float* __restrict__ A,
                                              const float* __restrict__ B,
                                              float* __restrict__ C, int M) {
    __shared__ float As[16][68];   // [k][row], padded: write conflicts <=2-way (free)
    __shared__ float Bs[16][64];   // [k][col]
    const int tid = threadIdx.x;
    const int tx = tid & 15, ty = tid >> 4;
    const int rowBase = blockIdx.x * 64;
    const int colBase = blockIdx.y * 64;

    const int arow = tid >> 2;            // 0..63
    const int acol = (tid & 3) << 2;      // 0,4,8,12
    const int grow = rowBase + arow;
    const float* aptr = A + (size_t)grow * K;

    float acc[4][4] = {{0.f}};

    for (int k0 = 0; k0 < K; k0 += 16) {
        float4 av = make_float4(0.f, 0.f, 0.f, 0.f);
        if (grow < M) av = *(const float4*)(aptr + k0 + acol);
        As[acol + 0][arow] = av.x;
        As[acol + 1][arow] = av.y;
        As[acol + 2][arow] = av.z;
        As[acol + 3][arow] = av.w;

        const int f = tid * 4;            // 1024 floats = 16x64 tile of B
        const int bk = f >> 6, bc = f & 63;
        float4 bv = *(const float4*)(B + (size_t)(k0 + bk) * NF + colBase + bc);
        *(float4*)&Bs[bk][bc] = bv;

        __syncthreads();
        #pragma unroll
        for (int kk = 0; kk < 16; ++kk) {
            const float4 a4 = *(const float4*)&As[kk][ty * 4];
            const float4 b4 = *(const float4*)&Bs[kk][tx * 4];
            const float a[4] = {a4.x, a4.y, a4.z, a4.w};
            const float b[4] = {b4.x, b4.y, b4.z, b4.w};
            #pragma unroll
            for (int i = 0; i < 4; ++i)
                #pragma unroll
                for (int j = 0; j < 4; ++j)
                    acc[i][j] = fmaf(a[i], b[j], acc[i][j]);
        }
        __syncthreads();
    }

    #pragma unroll
    for (int i = 0; i < 4; ++i) {
        int r = rowBase + ty * 4 + i;
        if (r < M) {
            float4 v = make_float4(acc[i][0], acc[i][1], acc[i][2], acc[i][3]);
            *(float4*)(C + (size_t)r * NF + colBase + tx * 4) = v;
        }
    }
}

// ---------------- layer-1 aggregation: h1 = relu(norm-agg(xw1) + b1) ----------------
// one block (256 thr) per node; thread t owns feature t.
__global__ __launch_bounds__(256) void k_agg1(const float* __restrict__ xw,
                                              const float* __restrict__ dinv,
                                              const int* __restrict__ offs,
                                              const int* __restrict__ degin,
                                              const int* __restrict__ csr,
                                              const float* __restrict__ b1,
                                              float* __restrict__ h1) {
    const int n = blockIdx.x;
    const int t = threadIdx.x;
    const float dn = dinv[n];
    float acc = dn * xw[(size_t)n * D_HID + t];   // self loop (dn factored out)
    const int start = offs[n];
    const int cnt = degin[n];
    int i = 0;
    for (; i + 2 <= cnt; i += 2) {
        int s0 = csr[start + i];
        int s1 = csr[start + i + 1];
        float w0 = dinv[s0], w1 = dinv[s1];
        float v0 = xw[(size_t)s0 * D_HID + t];
        float v1 = xw[(size_t)s1 * D_HID + t];
        acc = fmaf(w0, v0, acc);
        acc = fmaf(w1, v1, acc);
    }
    if (i < cnt) {
        int s0 = csr[start + i];
        acc = fmaf(dinv[s0], xw[(size_t)s0 * D_HID + t], acc);
    }
    float o = fmaf(acc, dn, b1[t]);
    h1[(size_t)n * D_HID + t] = fmaxf(o, 0.f);
}

// ---------------- layer-2 aggregation + bias + softmax ----------------
// one wave per node (4 nodes / block); lane = feature (D_OUT = 64).
__global__ __launch_bounds__(256) void k_agg2(const float* __restrict__ hw,
                                              const float* __restrict__ dinv,
                                              const int* __restrict__ offs,
                                              const int* __restrict__ degin,
                                              const int* __restrict__ csr,
                                              const float* __restrict__ b2,
                                              float* __restrict__ out) {
    const int wave = threadIdx.x >> 6;
    const int lane = threadIdx.x & 63;
    const int n = blockIdx.x * 4 + wave;   // 50000 = 12500*4, exact
    const float dn = dinv[n];
    float acc = dn * hw[(size_t)n * D_OUT + lane];
    const int start = offs[n];
    const int cnt = degin[n];
    int i = 0;
    for (; i + 2 <= cnt; i += 2) {
        int s0 = csr[start + i];
        int s1 = csr[start + i + 1];
        float w0 = dinv[s0], w1 = dinv[s1];
        float v0 = hw[(size_t)s0 * D_OUT + lane];
        float v1 = hw[(size_t)s1 * D_OUT + lane];
        acc = fmaf(w0, v0, acc);
        acc = fmaf(w1, v1, acc);
    }
    if (i < cnt) {
        int s0 = csr[start + i];
        acc = fmaf(dinv[s0], hw[(size_t)s0 * D_OUT + lane], acc);
    }
    float logit = fmaf(acc, dn, b2[lane]);
    float m = logit;
    #pragma unroll
    for (int d = 32; d > 0; d >>= 1) m = fmaxf(m, __shfl_xor(m, d));
    float e = expf(logit - m);
    float ssum = e;
    #pragma unroll
    for (int d = 32; d > 0; d >>= 1) ssum += __shfl_xor(ssum, d);
    out[(size_t)n * D_OUT + lane] = e / ssum;
}

// ---------------- launch ----------------

extern "C" void kernel_launch(void* const* d_in, const int* in_sizes, int n_in,
                              void* d_out, int out_size, void* d_ws, size_t ws_size,
                              hipStream_t stream) {
    const float* x  = (const float*)d_in[0];
    const int*   ei = (const int*)d_in[1];
    const float* W1 = (const float*)d_in[2];
    const float* b1 = (const float*)d_in[3];
    const float* W2 = (const float*)d_in[4];
    const float* b2 = (const float*)d_in[5];
    float* out = (float*)d_out;

    const int* src = ei;             // edge_index[0]
    const int* dst = ei + N_EDGES;   // edge_index[1]

    char* ws = (char*)d_ws;
    int*   counter = (int*)(ws + OFF_COUNTER);
    int*   deg     = (int*)(ws + OFF_DEG);
    float* dinv    = (float*)(ws + OFF_DINV);
    int*   offs    = (int*)(ws + OFF_OFFS);
    int*   cursor  = (int*)(ws + OFF_CURSOR);
    int*   csr     = (int*)(ws + OFF_CSR);
    float* xw1     = (float*)(ws + OFF_XW1);
    float* h1      = (float*)(ws + OFF_H1);
    float* hw2     = (float*)(ws + OFF_XW1);   // aliases xw1 (dead after agg1)

    // zero counter + deg
    hipMemsetAsync(ws, 0, OFF_DEG + N_NODES * sizeof(int), stream);

    k_hist<<<(N_EDGES + 255) / 256, 256, 0, stream>>>(dst, deg);
    k_scan<<<(N_NODES + 63) / 64, 64, 0, stream>>>(deg, dinv, offs, cursor, counter);
    k_scatter<<<(N_EDGES + 255) / 256, 256, 0, stream>>>(src, dst, cursor, csr);

    k_gemm<D_IN, D_HID><<<dim3((N_NODES + 63) / 64, D_HID / 64), 256, 0, stream>>>(x, W1, xw1, N_NODES);
    k_agg1<<<N_NODES, 256, 0, stream>>>(xw1, dinv, offs, deg, csr, b1, h1);
    k_gemm<D_HID, D_OUT><<<dim3((N_NODES + 63) / 64, D_OUT / 64), 256, 0, stream>>>(h1, W2, hw2, N_NODES);
    k_agg2<<<N_NODES / 4, 256, 0, stream>>>(hw2, dinv, offs, deg, csr, b2, out);
}

// Round 3
// 510.866 us; speedup vs baseline: 1.2055x; 1.2055x over previous
//
#include <hip/hip_runtime.h>
#include <hip/hip_bf16.h>
#include <math.h>

// ---------------------------------------------------------------------------
// 2-layer GCN on MI355X.
//   CSR build (hist -> wave-scan -> scatter)
//   xw1 = x @ W1      SPLIT-BF16 MFMA GEMM (x = hi+lo bf16, C ~= AhBh+AhBl+AlBh)
//   h1  = relu(sym-norm-agg(xw1) + b1)
//   hw2 = h1 @ W2     fp32 tiled GEMM
//   out = softmax(sym-norm-agg(hw2) + b2)
// ---------------------------------------------------------------------------

#define N_NODES 50000
#define N_EDGES 800000
#define D_IN    512
#define D_HID   256
#define D_OUT   64

#define OFF_COUNTER 0
#define OFF_DEG     256
#define OFF_DINV    (OFF_DEG + 200704)
#define OFF_OFFS    (OFF_DINV + 200704)
#define OFF_CURSOR  (OFF_OFFS + 200704)
#define OFF_CSR     (OFF_CURSOR + 200704)
#define OFF_XW1     (OFF_CSR + 3200000)
#define OFF_H1      (OFF_XW1 + 51200000)
// W1 split lives INSIDE the h1 region (dead until agg1 writes h1): 2 x 512KB
#define OFF_BHT     OFF_H1
#define OFF_BLT     (OFF_H1 + 524288)
// total ~106.4 MB

typedef __attribute__((ext_vector_type(8))) short bf16x8;
typedef __attribute__((ext_vector_type(4))) float f32x4;

// round-to-nearest-even fp32 -> bf16 bits
__device__ __forceinline__ unsigned int f2bf(float v) {
    unsigned int u = __float_as_uint(v);
    return (u + 0x7FFFu + ((u >> 16) & 1u)) >> 16;
}

// ---------------- CSR build ----------------

__global__ void k_hist(const int* __restrict__ dst, int* __restrict__ deg) {
    int e = blockIdx.x * 256 + threadIdx.x;
    if (e < N_EDGES) atomicAdd(&deg[dst[e]], 1);
}

__global__ void k_scan(const int* __restrict__ deg, float* __restrict__ dinv,
                       int* __restrict__ offs, int* __restrict__ cursor,
                       int* __restrict__ counter) {
    int lane = threadIdx.x;           // block = 64
    int i = blockIdx.x * 64 + lane;
    int v = (i < N_NODES) ? deg[i] : 0;
    if (i < N_NODES) dinv[i] = rsqrtf((float)(v + 1));   // +1 self loop
    int incl = v;
    #pragma unroll
    for (int d = 1; d < 64; d <<= 1) {
        int t = __shfl_up(incl, d);
        if (lane >= d) incl += t;
    }
    int total = __shfl(incl, 63);
    int base = 0;
    if (lane == 63) base = atomicAdd(counter, total);
    base = __shfl(base, 63);
    int off = base + incl - v;
    if (i < N_NODES) { offs[i] = off; cursor[i] = off; }
}

__global__ void k_scatter(const int* __restrict__ src, const int* __restrict__ dst,
                          int* __restrict__ cursor, int* __restrict__ csr) {
    int e = blockIdx.x * 256 + threadIdx.x;
    if (e < N_EDGES) {
        int d = dst[e];
        int slot = atomicAdd(&cursor[d], 1);
        csr[slot] = src[e];
    }
}

// ---------------- W1 split + transpose: W[512][256] -> hT/lT [256][512] bf16 ----
__global__ void k_splitW(const float* __restrict__ W, unsigned short* __restrict__ hT,
                         unsigned short* __restrict__ lT) {
    int idx = blockIdx.x * 256 + threadIdx.x;   // 131072 total
    int k = idx >> 8;
    int n = idx & 255;
    float v = W[idx];
    unsigned int h = f2bf(v);
    float hf = __uint_as_float(h << 16);
    unsigned int l = f2bf(v - hf);
    hT[n * 512 + k] = (unsigned short)h;
    lT[n * 512 + k] = (unsigned short)l;
}

// ---------------- GEMM1: C[M][256] = A[M][512] @ W1, split-bf16 MFMA ----------
// 128x128 tile, 256 threads (4 waves, each a 64x64 quadrant), BK=32.
// A reg-staged fp32->hi/lo bf16; LDS rows padded to 40 shorts (80 B) so frag
// ds_read_b128 bases spread over all 8 four-bank groups (conflict-free).
__global__ __launch_bounds__(256) void k_gemm1_mfma(const float* __restrict__ A,
        const unsigned short* __restrict__ BhT, const unsigned short* __restrict__ BlT,
        float* __restrict__ C, int M) {
    __shared__ unsigned short Ah[128][40];
    __shared__ unsigned short Al[128][40];
    __shared__ unsigned short Bh[128][40];   // [col][k]
    __shared__ unsigned short Bl[128][40];

    const int tid = threadIdx.x;
    const int lane = tid & 63;
    const int wave = tid >> 6;
    const int wrow = (wave >> 1) * 64;
    const int wcol = (wave & 1) * 64;
    const int rowBase = blockIdx.x * 128;
    const int colBase = blockIdx.y * 128;

    // A staging: thread -> (row, k-half of 16)
    const int arow = tid >> 1;
    const int ahalf = tid & 1;
    const int grow = rowBase + arow;
    const bool aval = (grow < M);
    const float* aptr = A + (size_t)grow * D_IN + ahalf * 16;

    // B staging: thread -> (col, k-half of 16); reads pre-split [col][k] arrays
    const int bcol = tid >> 1;
    const int bhalf = tid & 1;
    const unsigned short* bhptr = BhT + (size_t)(colBase + bcol) * D_IN + bhalf * 16;
    const unsigned short* blptr = BlT + (size_t)(colBase + bcol) * D_IN + bhalf * 16;

    f32x4 acc[4][4];
    #pragma unroll
    for (int i = 0; i < 4; ++i)
        #pragma unroll
        for (int j = 0; j < 4; ++j) acc[i][j] = (f32x4)0.f;

    const int l15 = lane & 15;
    const int g = lane >> 4;

    for (int k0 = 0; k0 < D_IN; k0 += 32) {
        // ---- stage A: 16 fp32 -> 16 hi + 16 lo bf16 ----
        float4 av0 = make_float4(0.f,0.f,0.f,0.f), av1 = av0, av2 = av0, av3 = av0;
        if (aval) {
            av0 = *(const float4*)(aptr + k0);
            av1 = *(const float4*)(aptr + k0 + 4);
            av2 = *(const float4*)(aptr + k0 + 8);
            av3 = *(const float4*)(aptr + k0 + 12);
        }
        float vv[16] = {av0.x,av0.y,av0.z,av0.w, av1.x,av1.y,av1.z,av1.w,
                        av2.x,av2.y,av2.z,av2.w, av3.x,av3.y,av3.z,av3.w};
        unsigned int hw_[8], lw_[8];
        #pragma unroll
        for (int e = 0; e < 8; ++e) {
            float v0 = vv[2*e], v1 = vv[2*e+1];
            unsigned int h0 = f2bf(v0), h1 = f2bf(v1);
            float r0 = v0 - __uint_as_float(h0 << 16);
            float r1 = v1 - __uint_as_float(h1 << 16);
            unsigned int l0 = f2bf(r0), l1 = f2bf(r1);
            hw_[e] = h0 | (h1 << 16);
            lw_[e] = l0 | (l1 << 16);
        }
        *(uint4*)&Ah[arow][ahalf*16]     = make_uint4(hw_[0],hw_[1],hw_[2],hw_[3]);
        *(uint4*)&Ah[arow][ahalf*16 + 8] = make_uint4(hw_[4],hw_[5],hw_[6],hw_[7]);
        *(uint4*)&Al[arow][ahalf*16]     = make_uint4(lw_[0],lw_[1],lw_[2],lw_[3]);
        *(uint4*)&Al[arow][ahalf*16 + 8] = make_uint4(lw_[4],lw_[5],lw_[6],lw_[7]);

        // ---- stage B (already bf16 in HBM/L2) ----
        uint4 bh0 = *(const uint4*)(bhptr + k0);
        uint4 bh1 = *(const uint4*)(bhptr + k0 + 8);
        uint4 bl0 = *(const uint4*)(blptr + k0);
        uint4 bl1 = *(const uint4*)(blptr + k0 + 8);
        *(uint4*)&Bh[bcol][bhalf*16]     = bh0;
        *(uint4*)&Bh[bcol][bhalf*16 + 8] = bh1;
        *(uint4*)&Bl[bcol][bhalf*16]     = bl0;
        *(uint4*)&Bl[bcol][bhalf*16 + 8] = bl1;

        __syncthreads();

        bf16x8 bhf[4], blf[4];
        #pragma unroll
        for (int j = 0; j < 4; ++j) {
            bhf[j] = *(const bf16x8*)&Bh[wcol + j*16 + l15][g*8];
            blf[j] = *(const bf16x8*)&Bl[wcol + j*16 + l15][g*8];
        }
        #pragma unroll
        for (int i = 0; i < 4; ++i) {
            bf16x8 ahf = *(const bf16x8*)&Ah[wrow + i*16 + l15][g*8];
            bf16x8 alf = *(const bf16x8*)&Al[wrow + i*16 + l15][g*8];
            #pragma unroll
            for (int j = 0; j < 4; ++j) {
                acc[i][j] = __builtin_amdgcn_mfma_f32_16x16x32_bf16(ahf, bhf[j], acc[i][j], 0, 0, 0);
                acc[i][j] = __builtin_amdgcn_mfma_f32_16x16x32_bf16(ahf, blf[j], acc[i][j], 0, 0, 0);
                acc[i][j] = __builtin_amdgcn_mfma_f32_16x16x32_bf16(alf, bhf[j], acc[i][j], 0, 0, 0);
            }
        }
        __syncthreads();
    }

    // epilogue: C/D layout col=lane&15, row=(lane>>4)*4+reg
    const int crow0 = rowBase + wrow + (lane >> 4) * 4;
    const int ccol = colBase + wcol + l15;
    #pragma unroll
    for (int i = 0; i < 4; ++i) {
        #pragma unroll
        for (int j = 0; j < 4; ++j) {
            #pragma unroll
            for (int r = 0; r < 4; ++r) {
                int m = crow0 + i * 16 + r;
                if (m < M) C[(size_t)m * D_HID + ccol + j * 16] = acc[i][j][r];
            }
        }
    }
}

// ---------------- fp32 tiled GEMM (kept for GEMM2) ----------------
template<int K, int NF>
__global__ __launch_bounds__(256) void k_gemm(const float* __restrict__ A,
                                              const float* __restrict__ B,
                                              float* __restrict__ C, int M) {
    __shared__ float As[16][68];
    __shared__ float Bs[16][64];
    const int tid = threadIdx.x;
    const int tx = tid & 15, ty = tid >> 4;
    const int rowBase = blockIdx.x * 64;
    const int colBase = blockIdx.y * 64;

    const int arow = tid >> 2;
    const int acol = (tid & 3) << 2;
    const int grow = rowBase + arow;
    const float* aptr = A + (size_t)grow * K;

    float acc[4][4] = {{0.f}};

    for (int k0 = 0; k0 < K; k0 += 16) {
        float4 av = make_float4(0.f, 0.f, 0.f, 0.f);
        if (grow < M) av = *(const float4*)(aptr + k0 + acol);
        As[acol + 0][arow] = av.x;
        As[acol + 1][arow] = av.y;
        As[acol + 2][arow] = av.z;
        As[acol + 3][arow] = av.w;

        const int f = tid * 4;
        const int bk = f >> 6, bc = f & 63;
        float4 bv = *(const float4*)(B + (size_t)(k0 + bk) * NF + colBase + bc);
        *(float4*)&Bs[bk][bc] = bv;

        __syncthreads();
        #pragma unroll
        for (int kk = 0; kk < 16; ++kk) {
            const float4 a4 = *(const float4*)&As[kk][ty * 4];
            const float4 b4 = *(const float4*)&Bs[kk][tx * 4];
            const float a[4] = {a4.x, a4.y, a4.z, a4.w};
            const float b[4] = {b4.x, b4.y, b4.z, b4.w};
            #pragma unroll
            for (int i = 0; i < 4; ++i)
                #pragma unroll
                for (int j = 0; j < 4; ++j)
                    acc[i][j] = fmaf(a[i], b[j], acc[i][j]);
        }
        __syncthreads();
    }

    #pragma unroll
    for (int i = 0; i < 4; ++i) {
        int r = rowBase + ty * 4 + i;
        if (r < M) {
            float4 v = make_float4(acc[i][0], acc[i][1], acc[i][2], acc[i][3]);
            *(float4*)(C + (size_t)r * NF + colBase + tx * 4) = v;
        }
    }
}

// ---------------- layer-1 aggregation ----------------
__global__ __launch_bounds__(256) void k_agg1(const float* __restrict__ xw,
                                              const float* __restrict__ dinv,
                                              const int* __restrict__ offs,
                                              const int* __restrict__ degin,
                                              const int* __restrict__ csr,
                                              const float* __restrict__ b1,
                                              float* __restrict__ h1) {
    const int n = blockIdx.x;
    const int t = threadIdx.x;
    const float dn = dinv[n];
    float acc = dn * xw[(size_t)n * D_HID + t];
    const int start = offs[n];
    const int cnt = degin[n];
    int i = 0;
    for (; i + 2 <= cnt; i += 2) {
        int s0 = csr[start + i];
        int s1 = csr[start + i + 1];
        float w0 = dinv[s0], w1 = dinv[s1];
        float v0 = xw[(size_t)s0 * D_HID + t];
        float v1 = xw[(size_t)s1 * D_HID + t];
        acc = fmaf(w0, v0, acc);
        acc = fmaf(w1, v1, acc);
    }
    if (i < cnt) {
        int s0 = csr[start + i];
        acc = fmaf(dinv[s0], xw[(size_t)s0 * D_HID + t], acc);
    }
    float o = fmaf(acc, dn, b1[t]);
    h1[(size_t)n * D_HID + t] = fmaxf(o, 0.f);
}

// ---------------- layer-2 aggregation + softmax ----------------
__global__ __launch_bounds__(256) void k_agg2(const float* __restrict__ hw,
                                              const float* __restrict__ dinv,
                                              const int* __restrict__ offs,
                                              const int* __restrict__ degin,
                                              const int* __restrict__ csr,
                                              const float* __restrict__ b2,
                                              float* __restrict__ out) {
    const int wave = threadIdx.x >> 6;
    const int lane = threadIdx.x & 63;
    const int n = blockIdx.x * 4 + wave;
    const float dn = dinv[n];
    float acc = dn * hw[(size_t)n * D_OUT + lane];
    const int start = offs[n];
    const int cnt = degin[n];
    int i = 0;
    for (; i + 2 <= cnt; i += 2) {
        int s0 = csr[start + i];
        int s1 = csr[start + i + 1];
        float w0 = dinv[s0], w1 = dinv[s1];
        float v0 = hw[(size_t)s0 * D_OUT + lane];
        float v1 = hw[(size_t)s1 * D_OUT + lane];
        acc = fmaf(w0, v0, acc);
        acc = fmaf(w1, v1, acc);
    }
    if (i < cnt) {
        int s0 = csr[start + i];
        acc = fmaf(dinv[s0], hw[(size_t)s0 * D_OUT + lane], acc);
    }
    float logit = fmaf(acc, dn, b2[lane]);
    float m = logit;
    #pragma unroll
    for (int d = 32; d > 0; d >>= 1) m = fmaxf(m, __shfl_xor(m, d));
    float e = expf(logit - m);
    float ssum = e;
    #pragma unroll
    for (int d = 32; d > 0; d >>= 1) ssum += __shfl_xor(ssum, d);
    out[(size_t)n * D_OUT + lane] = e / ssum;
}

// ---------------- launch ----------------

extern "C" void kernel_launch(void* const* d_in, const int* in_sizes, int n_in,
                              void* d_out, int out_size, void* d_ws, size_t ws_size,
                              hipStream_t stream) {
    const float* x  = (const float*)d_in[0];
    const int*   ei = (const int*)d_in[1];
    const float* W1 = (const float*)d_in[2];
    const float* b1 = (const float*)d_in[3];
    const float* W2 = (const float*)d_in[4];
    const float* b2 = (const float*)d_in[5];
    float* out = (float*)d_out;

    const int* src = ei;
    const int* dst = ei + N_EDGES;

    char* ws = (char*)d_ws;
    int*   counter = (int*)(ws + OFF_COUNTER);
    int*   deg     = (int*)(ws + OFF_DEG);
    float* dinv    = (float*)(ws + OFF_DINV);
    int*   offs    = (int*)(ws + OFF_OFFS);
    int*   cursor  = (int*)(ws + OFF_CURSOR);
    int*   csr     = (int*)(ws + OFF_CSR);
    float* xw1     = (float*)(ws + OFF_XW1);
    float* h1      = (float*)(ws + OFF_H1);
    float* hw2     = (float*)(ws + OFF_XW1);          // aliases xw1 (dead after agg1)
    unsigned short* BhT = (unsigned short*)(ws + OFF_BHT);  // inside h1 region
    unsigned short* BlT = (unsigned short*)(ws + OFF_BLT);  // (dead before agg1 writes h1)

    hipMemsetAsync(ws, 0, OFF_DEG + N_NODES * sizeof(int), stream);

    k_hist<<<(N_EDGES + 255) / 256, 256, 0, stream>>>(dst, deg);
    k_scan<<<(N_NODES + 63) / 64, 64, 0, stream>>>(deg, dinv, offs, cursor, counter);
    k_scatter<<<(N_EDGES + 255) / 256, 256, 0, stream>>>(src, dst, cursor, csr);

    k_splitW<<<512, 256, 0, stream>>>(W1, BhT, BlT);
    k_gemm1_mfma<<<dim3((N_NODES + 127) / 128, D_HID / 128), 256, 0, stream>>>(x, BhT, BlT, xw1, N_NODES);
    k_agg1<<<N_NODES, 256, 0, stream>>>(xw1, dinv, offs, deg, csr, b1, h1);
    k_gemm<D_HID, D_OUT><<<dim3((N_NODES + 63) / 64, D_OUT / 64), 256, 0, stream>>>(h1, W2, hw2, N_NODES);
    k_agg2<<<N_NODES / 4, 256, 0, stream>>>(hw2, dinv, offs, deg, csr, b2, out);
}

// Round 4
// 429.886 us; speedup vs baseline: 1.4326x; 1.1884x over previous
//
#include <hip/hip_runtime.h>
#include <hip/hip_bf16.h>
#include <math.h>

// ---------------------------------------------------------------------------
// 2-layer GCN on MI355X.
//   CSR build (hist -> wave-scan -> scatter)
//   xw1 = x @ W1    SPLIT-BF16 MFMA (x=hi+lo bf16; C ~= AhBh+AhBl+AlBh), OUT=bf16
//   h1  = relu(sym-norm-agg(xw1) + b1)   bf16 gather / bf16 out
//   hw2 = h1 @ W2   bf16 MFMA (W2 resident in LDS), OUT=fp32
//   out = softmax(sym-norm-agg(hw2) + b2)
// ---------------------------------------------------------------------------

#define N_NODES 50000
#define N_EDGES 800000
#define D_IN    512
#define D_HID   256
#define D_OUT   64

#define OFF_COUNTER 0
#define OFF_DEG     256
#define OFF_DINV    (OFF_DEG + 200704)
#define OFF_OFFS    (OFF_DINV + 200704)
#define OFF_CURSOR  (OFF_OFFS + 200704)
#define OFF_CSR     (OFF_CURSOR + 200704)
#define OFF_XW1     (OFF_CSR + 3200000)     // xw1 bf16 25.6MB; later hw2 fp32 12.8MB
#define OFF_H1      (OFF_XW1 + 51200000)    // h1 bf16 25.6MB
// W1 hi/lo split lives INSIDE the h1 region (dead before agg1 writes h1)
#define OFF_BHT     OFF_H1
#define OFF_BLT     (OFF_H1 + 524288)
#define OFF_W2T     (OFF_H1 + 25600000)     // W2T bf16 32KB (persists through gemm2)
// total ~105 MB (same footprint as previous rounds)

typedef __attribute__((ext_vector_type(8))) short bf16x8;
typedef __attribute__((ext_vector_type(4))) float f32x4;

// round-to-nearest-even fp32 -> bf16 bits
__device__ __forceinline__ unsigned int f2bf(float v) {
    unsigned int u = __float_as_uint(v);
    return (u + 0x7FFFu + ((u >> 16) & 1u)) >> 16;
}
__device__ __forceinline__ float bflo(unsigned int v) { return __uint_as_float(v << 16); }
__device__ __forceinline__ float bfhi(unsigned int v) { return __uint_as_float(v & 0xFFFF0000u); }

// ---------------- CSR build ----------------

__global__ void k_hist(const int* __restrict__ dst, int* __restrict__ deg) {
    int e = blockIdx.x * 256 + threadIdx.x;
    if (e < N_EDGES) atomicAdd(&deg[dst[e]], 1);
}

__global__ void k_scan(const int* __restrict__ deg, float* __restrict__ dinv,
                       int* __restrict__ offs, int* __restrict__ cursor,
                       int* __restrict__ counter) {
    int lane = threadIdx.x;           // block = 64
    int i = blockIdx.x * 64 + lane;
    int v = (i < N_NODES) ? deg[i] : 0;
    if (i < N_NODES) dinv[i] = rsqrtf((float)(v + 1));   // +1 self loop
    int incl = v;
    #pragma unroll
    for (int d = 1; d < 64; d <<= 1) {
        int t = __shfl_up(incl, d);
        if (lane >= d) incl += t;
    }
    int total = __shfl(incl, 63);
    int base = 0;
    if (lane == 63) base = atomicAdd(counter, total);
    base = __shfl(base, 63);
    int off = base + incl - v;
    if (i < N_NODES) { offs[i] = off; cursor[i] = off; }
}

__global__ void k_scatter(const int* __restrict__ src, const int* __restrict__ dst,
                          int* __restrict__ cursor, int* __restrict__ csr) {
    int e = blockIdx.x * 256 + threadIdx.x;
    if (e < N_EDGES) {
        int d = dst[e];
        int slot = atomicAdd(&cursor[d], 1);
        csr[slot] = src[e];
    }
}

// ---------------- W1 split + transpose: W[512][256] -> hT/lT [256][512] bf16 ----
__global__ void k_splitW(const float* __restrict__ W, unsigned short* __restrict__ hT,
                         unsigned short* __restrict__ lT) {
    int idx = blockIdx.x * 256 + threadIdx.x;   // 131072 total
    int k = idx >> 8;
    int n = idx & 255;
    float v = W[idx];
    unsigned int h = f2bf(v);
    float hf = __uint_as_float(h << 16);
    unsigned int l = f2bf(v - hf);
    hT[n * 512 + k] = (unsigned short)h;
    lT[n * 512 + k] = (unsigned short)l;
}

// ---------------- W2 transpose+bf16: W2[256][64] -> W2T[64][256] bf16 ----------
__global__ void k_prepW2(const float* __restrict__ W, unsigned short* __restrict__ T) {
    int idx = blockIdx.x * 256 + threadIdx.x;   // 16384 total
    int k = idx >> 6;
    int n = idx & 63;
    T[n * 256 + k] = (unsigned short)f2bf(W[idx]);
}

// ---------------- GEMM1: xw1[M][256](bf16) = A[M][512](f32) @ W1, split-bf16 ----
// 128x128 tile, 4 waves (64x64 quadrants), BK=32. LDS rows padded to 40 shorts.
__global__ __launch_bounds__(256) void k_gemm1_mfma(const float* __restrict__ A,
        const unsigned short* __restrict__ BhT, const unsigned short* __restrict__ BlT,
        unsigned short* __restrict__ C, int M) {
    __shared__ unsigned short Ah[128][40];
    __shared__ unsigned short Al[128][40];
    __shared__ unsigned short Bh[128][40];   // [col][k]
    __shared__ unsigned short Bl[128][40];

    const int tid = threadIdx.x;
    const int lane = tid & 63;
    const int wave = tid >> 6;
    const int wrow = (wave >> 1) * 64;
    const int wcol = (wave & 1) * 64;
    const int rowBase = blockIdx.x * 128;
    const int colBase = blockIdx.y * 128;

    const int arow = tid >> 1;
    const int ahalf = tid & 1;
    const int grow = rowBase + arow;
    const bool aval = (grow < M);
    const float* aptr = A + (size_t)grow * D_IN + ahalf * 16;

    const int bcol = tid >> 1;
    const int bhalf = tid & 1;
    const unsigned short* bhptr = BhT + (size_t)(colBase + bcol) * D_IN + bhalf * 16;
    const unsigned short* blptr = BlT + (size_t)(colBase + bcol) * D_IN + bhalf * 16;

    f32x4 acc[4][4];
    #pragma unroll
    for (int i = 0; i < 4; ++i)
        #pragma unroll
        for (int j = 0; j < 4; ++j) acc[i][j] = (f32x4)0.f;

    const int l15 = lane & 15;
    const int g = lane >> 4;

    for (int k0 = 0; k0 < D_IN; k0 += 32) {
        float4 av0 = make_float4(0.f,0.f,0.f,0.f), av1 = av0, av2 = av0, av3 = av0;
        if (aval) {
            av0 = *(const float4*)(aptr + k0);
            av1 = *(const float4*)(aptr + k0 + 4);
            av2 = *(const float4*)(aptr + k0 + 8);
            av3 = *(const float4*)(aptr + k0 + 12);
        }
        float vv[16] = {av0.x,av0.y,av0.z,av0.w, av1.x,av1.y,av1.z,av1.w,
                        av2.x,av2.y,av2.z,av2.w, av3.x,av3.y,av3.z,av3.w};
        unsigned int hw_[8], lw_[8];
        #pragma unroll
        for (int e = 0; e < 8; ++e) {
            float v0 = vv[2*e], v1 = vv[2*e+1];
            unsigned int h0 = f2bf(v0), h1 = f2bf(v1);
            float r0 = v0 - __uint_as_float(h0 << 16);
            float r1 = v1 - __uint_as_float(h1 << 16);
            unsigned int l0 = f2bf(r0), l1 = f2bf(r1);
            hw_[e] = h0 | (h1 << 16);
            lw_[e] = l0 | (l1 << 16);
        }
        *(uint4*)&Ah[arow][ahalf*16]     = make_uint4(hw_[0],hw_[1],hw_[2],hw_[3]);
        *(uint4*)&Ah[arow][ahalf*16 + 8] = make_uint4(hw_[4],hw_[5],hw_[6],hw_[7]);
        *(uint4*)&Al[arow][ahalf*16]     = make_uint4(lw_[0],lw_[1],lw_[2],lw_[3]);
        *(uint4*)&Al[arow][ahalf*16 + 8] = make_uint4(lw_[4],lw_[5],lw_[6],lw_[7]);

        uint4 bh0 = *(const uint4*)(bhptr + k0);
        uint4 bh1 = *(const uint4*)(bhptr + k0 + 8);
        uint4 bl0 = *(const uint4*)(blptr + k0);
        uint4 bl1 = *(const uint4*)(blptr + k0 + 8);
        *(uint4*)&Bh[bcol][bhalf*16]     = bh0;
        *(uint4*)&Bh[bcol][bhalf*16 + 8] = bh1;
        *(uint4*)&Bl[bcol][bhalf*16]     = bl0;
        *(uint4*)&Bl[bcol][bhalf*16 + 8] = bl1;

        __syncthreads();

        bf16x8 bhf[4], blf[4];
        #pragma unroll
        for (int j = 0; j < 4; ++j) {
            bhf[j] = *(const bf16x8*)&Bh[wcol + j*16 + l15][g*8];
            blf[j] = *(const bf16x8*)&Bl[wcol + j*16 + l15][g*8];
        }
        #pragma unroll
        for (int i = 0; i < 4; ++i) {
            bf16x8 ahf = *(const bf16x8*)&Ah[wrow + i*16 + l15][g*8];
            bf16x8 alf = *(const bf16x8*)&Al[wrow + i*16 + l15][g*8];
            #pragma unroll
            for (int j = 0; j < 4; ++j) {
                acc[i][j] = __builtin_amdgcn_mfma_f32_16x16x32_bf16(ahf, bhf[j], acc[i][j], 0, 0, 0);
                acc[i][j] = __builtin_amdgcn_mfma_f32_16x16x32_bf16(ahf, blf[j], acc[i][j], 0, 0, 0);
                acc[i][j] = __builtin_amdgcn_mfma_f32_16x16x32_bf16(alf, bhf[j], acc[i][j], 0, 0, 0);
            }
        }
        __syncthreads();
    }

    // epilogue -> bf16; C/D layout col=lane&15, row=(lane>>4)*4+reg
    const int crow0 = rowBase + wrow + (lane >> 4) * 4;
    const int ccol = colBase + wcol + l15;
    #pragma unroll
    for (int i = 0; i < 4; ++i) {
        #pragma unroll
        for (int j = 0; j < 4; ++j) {
            #pragma unroll
            for (int r = 0; r < 4; ++r) {
                int m = crow0 + i * 16 + r;
                if (m < M) C[(size_t)m * D_HID + ccol + j * 16] = (unsigned short)f2bf(acc[i][j][r]);
            }
        }
    }
}

// ---------------- layer-1 aggregation (bf16 in / bf16 out) ----------------
// one node per 128-thread block; thread t owns features 2t, 2t+1 (one uint).
__global__ __launch_bounds__(128) void k_agg1(const unsigned int* __restrict__ xw,
                                              const float* __restrict__ dinv,
                                              const int* __restrict__ offs,
                                              const int* __restrict__ degin,
                                              const int* __restrict__ csr,
                                              const float* __restrict__ b1,
                                              unsigned int* __restrict__ h1) {
    const int n = blockIdx.x;
    const int t = threadIdx.x;
    const float dn = dinv[n];
    unsigned int sv = xw[(size_t)n * 128 + t];
    float a0 = dn * bflo(sv);
    float a1 = dn * bfhi(sv);
    const int start = offs[n];
    const int cnt = degin[n];
    int i = 0;
    for (; i + 2 <= cnt; i += 2) {
        int s0 = csr[start + i];
        int s1 = csr[start + i + 1];
        float w0 = dinv[s0], w1 = dinv[s1];
        unsigned int v0 = xw[(size_t)s0 * 128 + t];
        unsigned int v1 = xw[(size_t)s1 * 128 + t];
        a0 = fmaf(w0, bflo(v0), a0);
        a1 = fmaf(w0, bfhi(v0), a1);
        a0 = fmaf(w1, bflo(v1), a0);
        a1 = fmaf(w1, bfhi(v1), a1);
    }
    if (i < cnt) {
        int s0 = csr[start + i];
        float w0 = dinv[s0];
        unsigned int v0 = xw[(size_t)s0 * 128 + t];
        a0 = fmaf(w0, bflo(v0), a0);
        a1 = fmaf(w0, bfhi(v0), a1);
    }
    float o0 = fmaxf(fmaf(a0, dn, b1[2 * t]), 0.f);
    float o1 = fmaxf(fmaf(a1, dn, b1[2 * t + 1]), 0.f);
    h1[(size_t)n * 128 + t] = f2bf(o0) | (f2bf(o1) << 16);
}

// ---------------- GEMM2: hw2[M][64](f32) = h1[M][256](bf16) @ W2 ----------------
// 128-row tile, 4 waves x 32 rows, W2T resident in LDS, BK=32, 8 K-steps.
__global__ __launch_bounds__(256) void k_gemm2_mfma(const unsigned short* __restrict__ A,
        const unsigned short* __restrict__ BT, float* __restrict__ C, int M) {
    __shared__ unsigned short As[128][40];
    __shared__ unsigned short Bs[64][260];   // [col][k], stride 520B: conflict-free

    const int tid = threadIdx.x;
    const int lane = tid & 63;
    const int wave = tid >> 6;
    const int wrow = wave * 32;
    const int rowBase = blockIdx.x * 128;

    // load entire W2T (16384 shorts) once: thread -> col=tid>>2, kq=(tid&3)*64
    {
        const int col = tid >> 2;
        const int kq = (tid & 3) * 64;
        const unsigned short* p = BT + (size_t)col * 256 + kq;
        #pragma unroll
        for (int u = 0; u < 8; ++u) {
            uint4 v = *(const uint4*)(p + u * 8);
            *(uint4*)&Bs[col][kq + u * 8] = v;
        }
    }

    const int arow = tid >> 1;
    const int ahalf = tid & 1;
    const int grow = rowBase + arow;
    const bool aval = (grow < M);
    const unsigned short* aptr = A + (size_t)grow * D_HID + ahalf * 16;

    f32x4 acc[2][4];
    #pragma unroll
    for (int i = 0; i < 2; ++i)
        #pragma unroll
        for (int j = 0; j < 4; ++j) acc[i][j] = (f32x4)0.f;

    const int l15 = lane & 15;
    const int g = lane >> 4;

    __syncthreads();   // Bs ready

    for (int k0 = 0; k0 < D_HID; k0 += 32) {
        uint4 z = make_uint4(0,0,0,0);
        uint4 a0 = z, a1 = z;
        if (aval) {
            a0 = *(const uint4*)(aptr + k0);
            a1 = *(const uint4*)(aptr + k0 + 8);
        }
        *(uint4*)&As[arow][ahalf*16]     = a0;
        *(uint4*)&As[arow][ahalf*16 + 8] = a1;
        __syncthreads();

        bf16x8 bf[4];
        #pragma unroll
        for (int j = 0; j < 4; ++j)
            bf[j] = *(const bf16x8*)&Bs[j*16 + l15][k0 + g*8];
        #pragma unroll
        for (int i = 0; i < 2; ++i) {
            bf16x8 af = *(const bf16x8*)&As[wrow + i*16 + l15][g*8];
            #pragma unroll
            for (int j = 0; j < 4; ++j)
                acc[i][j] = __builtin_amdgcn_mfma_f32_16x16x32_bf16(af, bf[j], acc[i][j], 0, 0, 0);
        }
        __syncthreads();
    }

    const int crow0 = rowBase + wrow + (lane >> 4) * 4;
    #pragma unroll
    for (int i = 0; i < 2; ++i) {
        #pragma unroll
        for (int j = 0; j < 4; ++j) {
            #pragma unroll
            for (int r = 0; r < 4; ++r) {
                int m = crow0 + i * 16 + r;
                if (m < M) C[(size_t)m * D_OUT + l15 + j * 16] = acc[i][j][r];
            }
        }
    }
}

// ---------------- layer-2 aggregation + softmax ----------------
__global__ __launch_bounds__(256) void k_agg2(const float* __restrict__ hw,
                                              const float* __restrict__ dinv,
                                              const int* __restrict__ offs,
                                              const int* __restrict__ degin,
                                              const int* __restrict__ csr,
                                              const float* __restrict__ b2,
                                              float* __restrict__ out) {
    const int wave = threadIdx.x >> 6;
    const int lane = threadIdx.x & 63;
    const int n = blockIdx.x * 4 + wave;
    const float dn = dinv[n];
    float acc = dn * hw[(size_t)n * D_OUT + lane];
    const int start = offs[n];
    const int cnt = degin[n];
    int i = 0;
    for (; i + 2 <= cnt; i += 2) {
        int s0 = csr[start + i];
        int s1 = csr[start + i + 1];
        float w0 = dinv[s0], w1 = dinv[s1];
        float v0 = hw[(size_t)s0 * D_OUT + lane];
        float v1 = hw[(size_t)s1 * D_OUT + lane];
        acc = fmaf(w0, v0, acc);
        acc = fmaf(w1, v1, acc);
    }
    if (i < cnt) {
        int s0 = csr[start + i];
        acc = fmaf(dinv[s0], hw[(size_t)s0 * D_OUT + lane], acc);
    }
    float logit = fmaf(acc, dn, b2[lane]);
    float m = logit;
    #pragma unroll
    for (int d = 32; d > 0; d >>= 1) m = fmaxf(m, __shfl_xor(m, d));
    float e = expf(logit - m);
    float ssum = e;
    #pragma unroll
    for (int d = 32; d > 0; d >>= 1) ssum += __shfl_xor(ssum, d);
    out[(size_t)n * D_OUT + lane] = e / ssum;
}

// ---------------- launch ----------------

extern "C" void kernel_launch(void* const* d_in, const int* in_sizes, int n_in,
                              void* d_out, int out_size, void* d_ws, size_t ws_size,
                              hipStream_t stream) {
    const float* x  = (const float*)d_in[0];
    const int*   ei = (const int*)d_in[1];
    const float* W1 = (const float*)d_in[2];
    const float* b1 = (const float*)d_in[3];
    const float* W2 = (const float*)d_in[4];
    const float* b2 = (const float*)d_in[5];
    float* out = (float*)d_out;

    const int* src = ei;
    const int* dst = ei + N_EDGES;

    char* ws = (char*)d_ws;
    int*   counter = (int*)(ws + OFF_COUNTER);
    int*   deg     = (int*)(ws + OFF_DEG);
    float* dinv    = (float*)(ws + OFF_DINV);
    int*   offs    = (int*)(ws + OFF_OFFS);
    int*   cursor  = (int*)(ws + OFF_CURSOR);
    int*   csr     = (int*)(ws + OFF_CSR);
    unsigned short* xw1b = (unsigned short*)(ws + OFF_XW1);   // bf16 [N][256]
    unsigned short* h1b  = (unsigned short*)(ws + OFF_H1);    // bf16 [N][256]
    float* hw2 = (float*)(ws + OFF_XW1);                      // f32 [N][64], aliases xw1b
    unsigned short* BhT = (unsigned short*)(ws + OFF_BHT);    // inside h1 region (dead early)
    unsigned short* BlT = (unsigned short*)(ws + OFF_BLT);
    unsigned short* W2T = (unsigned short*)(ws + OFF_W2T);

    hipMemsetAsync(ws, 0, OFF_DEG + N_NODES * sizeof(int), stream);

    k_hist<<<(N_EDGES + 255) / 256, 256, 0, stream>>>(dst, deg);
    k_scan<<<(N_NODES + 63) / 64, 64, 0, stream>>>(deg, dinv, offs, cursor, counter);
    k_scatter<<<(N_EDGES + 255) / 256, 256, 0, stream>>>(src, dst, cursor, csr);

    k_splitW<<<512, 256, 0, stream>>>(W1, BhT, BlT);
    k_prepW2<<<64, 256, 0, stream>>>(W2, W2T);

    k_gemm1_mfma<<<dim3((N_NODES + 127) / 128, D_HID / 128), 256, 0, stream>>>(x, BhT, BlT, xw1b, N_NODES);
    k_agg1<<<N_NODES, 128, 0, stream>>>((const unsigned int*)xw1b, dinv, offs, deg, csr, b1, (unsigned int*)h1b);
    k_gemm2_mfma<<<(N_NODES + 127) / 128, 256, 0, stream>>>(h1b, W2T, hw2, N_NODES);
    k_agg2<<<N_NODES / 4, 256, 0, stream>>>(hw2, dinv, offs, deg, csr, b2, out);
}